// Round 19
// baseline (106.986 us; speedup 1.0000x reference)
//
#include <hip/hip_runtime.h>
#include <math.h>

// QuanvolutionHybrid: conv2x2/s2 -> reshape(196,4) -> L2 norm ->
// all-pairs cos^2 >= 0.8 -> degree -> concat(784+196) -> linear(10) -> log_softmax
// R19: FOUR images per block (grid 2048). R18's per-image math kept verbatim
//      (192-aligned MFMA core, boundary ballot strip, pinned zacc, plain-C
//      counting). Deltas: no s_x staging (conv reads global directly, fully
//      coalesced row float2s), 24 jobs = 6/wave balanced, barriers/image
//      3.5 -> 1.5, lin_w loads amortized 4x. LDS 38.3KB -> 4 blocks/CU.

#define NP 196
#define FEAT 980
#define COS_TH 0.894427190999915878f   // sqrt(0.8)

typedef short v4s  __attribute__((ext_vector_type(4)));
typedef short v8s  __attribute__((ext_vector_type(8)));
typedef float v16f __attribute__((ext_vector_type(16)));

static __device__ __forceinline__ float bf2f(short s) {
    return __uint_as_float(((uint32_t)(uint16_t)s) << 16);
}

__global__ __launch_bounds__(256, 4) void quanv_kernel(
    const float* __restrict__ x,        // (8192, 784)
    const float* __restrict__ conv_w,   // (4,1,2,2) = 16
    const float* __restrict__ conv_b,   // (4,)
    const float* __restrict__ lin_w,    // (10, 980)
    const float* __restrict__ lin_b,    // (10,)
    float* __restrict__ out)            // (8192, 10)
{
    __shared__ __align__(16) short s_P[4][256][8];   // bf16 h0..h3,l0..l3; rows>=196 zero
    __shared__ __align__(16) float s_feats[4][FEAT];
    __shared__ int s_deg[4][192];
    __shared__ int s_cred[4][196];
    // s_P dead after phase 4b -> overlay the linear-phase buffers on it.
    float* s_part   = (float*)s_P;          // [4][250]
    float* s_logits = (float*)s_P + 1000;   // [4][10]

    const int b = blockIdx.x;            // 2048 blocks, 4 images each
    const int t = threadIdx.x;
    const int w = t >> 6, l = t & 63;

    // ---- Phase 2: conv straight from global (coalesced float2 rows) ----
    if (t < NP) {
        int h = t / 14, ww = t - 14 * (t / 14);
        #pragma unroll
        for (int img = 0; img < 4; ++img) {
            const float* ib = x + (size_t)(4 * b + img) * 784 + 56 * h + 2 * ww;
            float2 r0 = *(const float2*)(ib);
            float2 r1 = *(const float2*)(ib + 28);
            #pragma unroll
            for (int c = 0; c < 4; ++c) {
                float f = conv_b[c]
                        + conv_w[c * 4 + 0] * r0.x + conv_w[c * 4 + 1] * r0.y
                        + conv_w[c * 4 + 2] * r1.x + conv_w[c * 4 + 3] * r1.y;
                s_feats[img][c * NP + t] = f;
            }
        }
    }
    __syncthreads();

    // ---- Phase 3: normalize + exact bf16 hi/lo split -> s_P; zero pads/cred ----
    {
        #pragma unroll
        for (int img = 0; img < 4; ++img) {
            v8s pk = {0, 0, 0, 0, 0, 0, 0, 0};
            if (t < NP) {
                float4 v = ((const float4*)s_feats[img])[t];
                float n = sqrtf(v.x * v.x + v.y * v.y + v.z * v.z + v.w * v.w);
                float inv = 1.0f / (n + 1e-12f);
                float e[4] = { v.x * inv, v.y * inv, v.z * inv, v.w * inv };
                #pragma unroll
                for (int k = 0; k < 4; ++k) {
                    uint32_t bx = __float_as_uint(e[k]);
                    uint32_t rh = bx + 0x7FFFu + ((bx >> 16) & 1u);   // RNE bf16
                    uint32_t hk = rh >> 16;
                    float hif = __uint_as_float(hk << 16);
                    float res = e[k] - hif;                            // exact
                    uint32_t br = __float_as_uint(res);
                    uint32_t rl = br + 0x7FFFu + ((br >> 16) & 1u);
                    pk[k]     = (short)hk;
                    pk[4 + k] = (short)(rl >> 16);
                }
            }
            *(v8s*)&s_P[img][t][0] = pk;
        }
        if (t < NP) {
            s_cred[0][t] = 0; s_cred[1][t] = 0;
            s_cred[2][t] = 0; s_cred[3][t] = 0;
        }
    }
    __syncthreads();

    // Persistent zero C-operand (R16): built once, pinned.
    v16f zacc = {0.f,0.f,0.f,0.f,0.f,0.f,0.f,0.f,
                 0.f,0.f,0.f,0.f,0.f,0.f,0.f,0.f};
    asm("" : "+v"(zacc));

    const int ln = l & 31, half = l >> 5;

    // ---- Phase 4a: MFMA core rows/cols 0..191. 24 jobs (4img x 6 colstripes),
    //      wave w takes jobs w+4*jj -> exactly 6, perfectly balanced. ----
    #pragma unroll
    for (int jj = 0; jj < 6; ++jj) {
        const int job = w + 4 * jj;          // 0..23, wave-uniform
        const int img = job / 6;
        const int j = job - 6 * img;
        const short* Pbase = &s_P[img][0][0];

        v4s bh = *(const v4s*)(Pbase + (32 * j + ln) * 8 + 4 * half);
        v8s B = __builtin_shufflevector(bh, bh, 0, 1, 2, 3, 0, 1, 2, 3);

        unsigned c0 = 0u, c1 = 0u;
        #pragma unroll
        for (int i = 0; i < 6; ++i) {
            v8s A = *(const v8s*)(Pbase + (32 * i + ln) * 8);
            v16f acc = __builtin_amdgcn_mfma_f32_32x32x16_bf16(A, B, zacc, 0, 0, 0);
            #pragma unroll
            for (int e = 0; e < 16; e += 2) {
                c0 += (fabsf(acc[e])     >= COS_TH) ? 1u : 0u;
                c1 += (fabsf(acc[e + 1]) >= COS_TH) ? 1u : 0u;
            }
        }
        unsigned cnt = c0 + c1;
        cnt += __shfl_down(cnt, 32, 64);   // merge the two row-halves
        if (l < 32)
            s_deg[img][32 * j + l] = (int)cnt;
    }

    // ---- Phase 4b: boundary rows 192..195 (wave w owns row 192+w, each img).
    #pragma unroll
    for (int img = 0; img < 4; ++img) {
        const int r = 192 + w;
        const short* pr = &s_P[img][r][0];
        float pe0 = bf2f(pr[0]) + bf2f(pr[4]);
        float pe1 = bf2f(pr[1]) + bf2f(pr[5]);
        float pe2 = bf2f(pr[2]) + bf2f(pr[6]);
        float pe3 = bf2f(pr[3]) + bf2f(pr[7]);
        unsigned total = 0u;
        #pragma unroll
        for (int k = 0; k < 4; ++k) {
            int q = 64 * k + l;              // rows >=196 are zero -> miss
            const short* qr = &s_P[img][q][0];
            float d =          pe0 * (bf2f(qr[0]) + bf2f(qr[4]));
            d = fmaf(pe1, bf2f(qr[1]) + bf2f(qr[5]), d);
            d = fmaf(pe2, bf2f(qr[2]) + bf2f(qr[6]), d);
            d = fmaf(pe3, bf2f(qr[3]) + bf2f(qr[7]), d);
            bool hit = fabsf(d) >= COS_TH;
            unsigned long long m = __ballot(hit);
            total += (unsigned)__popcll(m);
            if (hit && q < 192)
                atomicAdd(&s_cred[img][q], 1);   // sparse (~4%)
        }
        if (l == 0)
            s_feats[img][784 + r] = (float)(int)total - 1.0f;  // self-edge
    }
    __syncthreads();

    // ---- Phase 4c: combine core counts + boundary credits -> deg features ----
    if (t < 192) {
        #pragma unroll
        for (int img = 0; img < 4; ++img)
            s_feats[img][784 + t] = (float)(s_deg[img][t] + s_cred[img][t]) - 1.0f;
    }
    __syncthreads();

    // ---- Phase 5: linear, each lin_w float4 loaded once for all 4 images ----
    if (t < 250) {
        int k = t / 25, c = t - 25 * (t / 25);
        const float4* wrow = (const float4*)(lin_w + k * FEAT);
        const float4* f0p = (const float4*)s_feats[0];
        const float4* f1p = (const float4*)s_feats[1];
        const float4* f2p = (const float4*)s_feats[2];
        const float4* f3p = (const float4*)s_feats[3];
        float a0 = 0.f, a1 = 0.f, a2 = 0.f, a3 = 0.f;
        for (int i = c; i < 245; i += 25) {
            float4 wv = wrow[i];
            float4 v0 = f0p[i], v1 = f1p[i], v2 = f2p[i], v3 = f3p[i];
            a0 = fmaf(v0.x, wv.x, a0); a1 = fmaf(v1.x, wv.x, a1);
            a2 = fmaf(v2.x, wv.x, a2); a3 = fmaf(v3.x, wv.x, a3);
            a0 = fmaf(v0.y, wv.y, a0); a1 = fmaf(v1.y, wv.y, a1);
            a2 = fmaf(v2.y, wv.y, a2); a3 = fmaf(v3.y, wv.y, a3);
            a0 = fmaf(v0.z, wv.z, a0); a1 = fmaf(v1.z, wv.z, a1);
            a2 = fmaf(v2.z, wv.z, a2); a3 = fmaf(v3.z, wv.z, a3);
            a0 = fmaf(v0.w, wv.w, a0); a1 = fmaf(v1.w, wv.w, a1);
            a2 = fmaf(v2.w, wv.w, a2); a3 = fmaf(v3.w, wv.w, a3);
        }
        s_part[t]       = a0;
        s_part[250 + t] = a1;
        s_part[500 + t] = a2;
        s_part[750 + t] = a3;
    }
    __syncthreads();

    if (t < 40) {
        int img = t / 10, k = t - 10 * (t / 10);
        const float* part = s_part + 250 * img;
        float s = lin_b[k];
        #pragma unroll
        for (int i = 0; i < 25; ++i) s += part[k * 25 + i];
        s_logits[10 * img + k] = s;
    }
    __syncthreads();

    // ---- Phase 6: log_softmax, all 4 images in parallel lanes ----
    if (t < 40) {
        int img = t / 10, k = t - 10 * (t / 10);
        const float* lg = s_logits + 10 * img;
        float m = -INFINITY;
        #pragma unroll
        for (int j2 = 0; j2 < 10; ++j2) m = fmaxf(m, lg[j2]);
        float s = 0.0f;
        #pragma unroll
        for (int j2 = 0; j2 < 10; ++j2) s += expf(lg[j2] - m);
        out[(size_t)(4 * b + img) * 10 + k] = lg[k] - m - logf(s);
    }
}

extern "C" void kernel_launch(void* const* d_in, const int* in_sizes, int n_in,
                              void* d_out, int out_size, void* d_ws, size_t ws_size,
                              hipStream_t stream) {
    const float* x      = (const float*)d_in[0];
    const float* conv_w = (const float*)d_in[1];
    const float* conv_b = (const float*)d_in[2];
    const float* lin_w  = (const float*)d_in[3];
    const float* lin_b  = (const float*)d_in[4];
    float* out = (float*)d_out;
    quanv_kernel<<<dim3(2048), dim3(256), 0, stream>>>(x, conv_w, conv_b, lin_w, lin_b, out);
}